// Round 3
// baseline (350.667 us; speedup 1.0000x reference)
//
#include <hip/hip_runtime.h>
#include <stdint.h>

#define T_STEPS 256
#define F_IN 64
#define L2E 1.44269504f

typedef __bf16 bf16x8 __attribute__((ext_vector_type(8)));
typedef float f32x4 __attribute__((ext_vector_type(4)));
typedef uint32_t u32;
typedef uint32_t u32x2 __attribute__((ext_vector_type(2)));

#define GLDS16(gp, lp)                                                         \
    __builtin_amdgcn_global_load_lds(                                          \
        (const __attribute__((address_space(1))) unsigned int*)(gp),           \
        (__attribute__((address_space(3))) unsigned int*)(lp), 16, 0, 0)

static __device__ __forceinline__ u32 pk2(float lo, float hi) {
    unsigned short a = __builtin_bit_cast(unsigned short, (__bf16)lo);
    unsigned short b = __builtin_bit_cast(unsigned short, (__bf16)hi);
    return (u32)a | ((u32)b << 16);
}

// 2 waves per 16-row tile. Wave 0 owns gate-tiles 0..3 (i,j); wave 1 owns 4..7 (f,o).
// Transposed MFMA: gates^T[g][16] = W^T[g][96] @ [x|h]^T[96][16]
// A-frag (W^T): elem j of lane l -> W^T[gate=gt*16+(l&15)][k=(l>>4)*8+j]
// B-frag (x/h): elem j of lane l -> [x|h]^T[k=(l>>4)*8+j][batch=l&15]
// D          : elem r of lane l -> gates^T[gate=gt*16+(l>>4)*4+r][batch=l&15]
__global__ __launch_bounds__(128, 2)
void lstm_fused(const float* __restrict__ x,
                const float* __restrict__ Wl,   // [96][128]
                const float* __restrict__ bl,   // [128]
                const float* __restrict__ Wd,   // [32]
                const float* __restrict__ bd,   // [1]
                float* __restrict__ out)        // [B]
{
    __shared__ __align__(16) float  xs[4][1024];   // 16 KB x ring (4 KB/step)
    __shared__ __align__(16) float  PX [64][4];    // A->B : P[uh=1] fp32
    __shared__ __align__(16) float  SQS[64][4];    // B->A : S[uh=0]
    __shared__ __align__(16) float  SQO[64][4];    // B->A : O[uh=0]
    __shared__ __align__(16) __bf16 hf [64][8];    // h as MFMA B-frag layout

    const int lane = threadIdx.x & 63;
    const int wid  = threadIdx.x >> 6;             // 0 = i/j wave, 1 = f/o wave
    const int cl   = lane & 15;
    const int g4   = lane >> 4;
    const int rowBase = blockIdx.x * 16;

    // ---- this wave's 12 W^T A-fragments ----
    bf16x8 wfrag[3][4];
#pragma unroll
    for (int kc = 0; kc < 3; ++kc) {
#pragma unroll
        for (int q = 0; q < 4; ++q) {
            bf16x8 v;
#pragma unroll
            for (int j = 0; j < 8; ++j)
                v[j] = (__bf16)Wl[(kc * 32 + g4 * 8 + j) * 128 + (wid * 4 + q) * 16 + cl];
            wfrag[kc][q] = v;
        }
    }

    // ---- folded bias constants (unit u = uh*16 + g4*4 + r) ----
    // wave0: K0 = -L2E*bi            K1 = -2*L2E*bj
    // wave1: K0 = -L2E*(bf+1)        K1 = -L2E*bo
    float K0[2][4], K1[2][4];
    {
        const float* bb   = bl + wid * 64;
        const float  addf = wid ? 1.0f : 0.0f;
        const float  s1   = wid ? -L2E : -2.0f * L2E;
#pragma unroll
        for (int uh = 0; uh < 2; ++uh)
#pragma unroll
            for (int r = 0; r < 4; ++r) {
                K0[uh][r] = -L2E * (bb[uh * 16 + g4 * 4 + r] + addf);
                K1[uh][r] = s1 * bb[32 + uh * 16 + g4 * 4 + r];
            }
    }
    const float bd0 = bd[0];
    const f32x4 wdA = *(const f32x4*)(Wd + g4 * 8);
    const f32x4 wdB = *(const f32x4*)(Wd + g4 * 8 + 4);

    // per-lane pre-swizzled global base; this wave fetches float-chunks [wid*32, wid*32+32)
    const float* gbase = x + (size_t)(rowBase + (lane >> 2)) * (size_t)(T_STEPS * F_IN)
                           + (size_t)(((lane & 3) ^ ((lane >> 3) & 3)) * 4);

    asm volatile("s_waitcnt vmcnt(0)" ::: "memory");   // drain setup loads
    __builtin_amdgcn_sched_barrier(0);

    // my hf word slots (disjoint per wave): h[u0..u0+3] for u0 = (lane>>4)*4 + 16*wid
    const int tT = ((lane >> 5) + 2 * wid) * 16 + (lane & 15);
    const int e0 = 4 * ((lane >> 4) & 1);
    *reinterpret_cast<u32x2*>(&hf[tT][e0]) = u32x2{0u, 0u};   // h0 = 0

    // prologue prefetch: slots 0..2, 2 loads/wave/slot
#pragma unroll
    for (int s = 0; s < 3; ++s) {
        const float* gp = gbase + s * F_IN + wid * 32;
        GLDS16(gp,      &xs[s][wid * 512]);
        GLDS16(gp + 16, &xs[s][wid * 512 + 256]);
    }

    asm volatile("s_waitcnt vmcnt(4)" ::: "memory");   // own slot-0 loads done
    asm volatile("s_waitcnt lgkmcnt(0)" ::: "memory"); // hf zeros visible
    __builtin_amdgcn_sched_barrier(0);
    __builtin_amdgcn_s_barrier();
    __builtin_amdgcn_sched_barrier(0);

    const int swz = (cl >> 1) & 3;
    const int c0  = ((g4 & 1) * 2)     ^ swz;
    const int c1  = ((g4 & 1) * 2 + 1) ^ swz;
    const int kA  = (g4 >> 1) * 256 + cl * 16;
    const int kB  = kA + 512;
    const f32x4 z4 = {0.f, 0.f, 0.f, 0.f};

    float c_st[4] = {0.f, 0.f, 0.f, 0.f};

#define STEP(TT, SLOT) do {                                                    \
    /* ---- phase 1 ---- */                                                    \
    const int tpf = ((TT) + 3 < T_STEPS) ? (TT) + 3 : T_STEPS - 1;             \
    const float* gp = gbase + tpf * F_IN + wid * 32;                           \
    GLDS16(gp,      &xs[((SLOT)+3)&3][wid * 512]);                             \
    GLDS16(gp + 16, &xs[((SLOT)+3)&3][wid * 512 + 256]);                       \
    const float* sl = &xs[SLOT][0];                                            \
    f32x4 xr0 = *(const f32x4*)(sl + kA + c0 * 4);                             \
    f32x4 xr1 = *(const f32x4*)(sl + kA + c1 * 4);                             \
    f32x4 xr2 = *(const f32x4*)(sl + kB + c0 * 4);                             \
    f32x4 xr3 = *(const f32x4*)(sl + kB + c1 * 4);                             \
    bf16x8 ah = *reinterpret_cast<const bf16x8*>(&hf[lane][0]);                \
    bf16x8 ax0, ax1;                                                           \
    _Pragma("unroll")                                                          \
    for (int j = 0; j < 4; ++j) {                                              \
        ax0[j]     = (__bf16)xr0[j];                                           \
        ax0[4 + j] = (__bf16)xr1[j];                                           \
        ax1[j]     = (__bf16)xr2[j];                                           \
        ax1[4 + j] = (__bf16)xr3[j];                                           \
    }                                                                          \
    f32x4 acc[4];                                                              \
    __builtin_amdgcn_s_setprio(1);                                             \
    _Pragma("unroll")                                                          \
    for (int q = 0; q < 4; ++q) {                                              \
        f32x4 a = __builtin_amdgcn_mfma_f32_16x16x32_bf16(wfrag[0][q], ax0, z4, 0, 0, 0); \
        a = __builtin_amdgcn_mfma_f32_16x16x32_bf16(wfrag[1][q], ax1, a, 0, 0, 0);        \
        a = __builtin_amdgcn_mfma_f32_16x16x32_bf16(wfrag[2][q], ah,  a, 0, 0, 0);        \
        acc[q] = a;                                                            \
    }                                                                          \
    __builtin_amdgcn_s_setprio(0);                                             \
    float Pl[2][4], Sl[2][4], Ol[2][4];                                        \
    if (wid == 0) {                                                            \
        _Pragma("unroll")                                                      \
        for (int uh = 0; uh < 2; ++uh)                                         \
        _Pragma("unroll")                                                      \
        for (int r = 0; r < 4; ++r) {                                          \
            float I = __builtin_amdgcn_exp2f(__builtin_fmaf(acc[uh][r],     -L2E,        K0[uh][r])); \
            float J = __builtin_amdgcn_exp2f(__builtin_fmaf(acc[2 + uh][r], -2.0f * L2E, K1[uh][r])); \
            float D = __builtin_amdgcn_rcpf((1.0f + I) * (1.0f + J));          \
            Pl[uh][r] = (1.0f - J) * D;                                        \
        }                                                                      \
        *(f32x4*)&PX[lane][0] = f32x4{Pl[1][0], Pl[1][1], Pl[1][2], Pl[1][3]}; \
    } else {                                                                   \
        _Pragma("unroll")                                                      \
        for (int uh = 0; uh < 2; ++uh)                                         \
        _Pragma("unroll")                                                      \
        for (int r = 0; r < 4; ++r) {                                          \
            float Fv = __builtin_amdgcn_exp2f(__builtin_fmaf(acc[uh][r],     -L2E, K0[uh][r])); \
            Sl[uh][r] = __builtin_amdgcn_rcpf(1.0f + Fv);                      \
            Ol[uh][r] = __builtin_amdgcn_exp2f(__builtin_fmaf(acc[2 + uh][r], -L2E, K1[uh][r])); \
        }                                                                      \
        *(f32x4*)&SQS[lane][0] = f32x4{Sl[0][0], Sl[0][1], Sl[0][2], Sl[0][3]};\
        *(f32x4*)&SQO[lane][0] = f32x4{Ol[0][0], Ol[0][1], Ol[0][2], Ol[0][3]};\
    }                                                                          \
    asm volatile("s_waitcnt lgkmcnt(0)" ::: "memory");                         \
    __builtin_amdgcn_sched_barrier(0);                                         \
    __builtin_amdgcn_s_barrier();                                              \
    __builtin_amdgcn_sched_barrier(0);                                         \
    /* ---- phase 2: my cells are uh = wid ---- */                             \
    f32x4 Pm, Sv, Ov;                                                          \
    if (wid == 0) {                                                            \
        Pm = f32x4{Pl[0][0], Pl[0][1], Pl[0][2], Pl[0][3]};                    \
        Sv = *(const f32x4*)&SQS[lane][0];                                     \
        Ov = *(const f32x4*)&SQO[lane][0];                                     \
    } else {                                                                   \
        Pm = *(const f32x4*)&PX[lane][0];                                      \
        Sv = f32x4{Sl[1][0], Sl[1][1], Sl[1][2], Sl[1][3]};                    \
        Ov = f32x4{Ol[1][0], Ol[1][1], Ol[1][2], Ol[1][3]};                    \
    }                                                                          \
    float hh[4];                                                               \
    _Pragma("unroll")                                                          \
    for (int r = 0; r < 4; ++r) {                                              \
        float cn = __builtin_fmaf(c_st[r], Sv[r], Pm[r]);                      \
        float C  = __builtin_amdgcn_exp2f(-2.0f * L2E * cn);                   \
        float dr = __builtin_amdgcn_rcpf((1.0f + C) * (1.0f + Ov[r]));         \
        hh[r] = (1.0f - C) * dr;                                               \
        c_st[r] = cn;                                                          \
    }                                                                          \
    *reinterpret_cast<u32x2*>(&hf[tT][e0]) =                                   \
        u32x2{pk2(hh[0], hh[1]), pk2(hh[2], hh[3])};                           \
    asm volatile("s_waitcnt vmcnt(4)" ::: "memory");                           \
    asm volatile("s_waitcnt lgkmcnt(0)" ::: "memory");                         \
    __builtin_amdgcn_sched_barrier(0);                                         \
    __builtin_amdgcn_s_barrier();                                              \
    __builtin_amdgcn_sched_barrier(0);                                         \
} while (0)

    for (int t = 0; t < T_STEPS; t += 4) {
        STEP(t,     0);
        STEP(t + 1, 1);
        STEP(t + 2, 2);
        STEP(t + 3, 3);
    }
#undef STEP

    // ---- epilogue: out[b] = ELU(sum_u h[u]*Wd[u] + bd), read h from frag LDS ----
    if (wid == 0) {
        bf16x8 hfin = *reinterpret_cast<const bf16x8*>(&hf[lane][0]);
        float v = 0.f;
#pragma unroll
        for (int j = 0; j < 4; ++j) {
            v = __builtin_fmaf((float)hfin[j],     wdA[j], v);
            v = __builtin_fmaf((float)hfin[4 + j], wdB[j], v);
        }
        v += __shfl_xor(v, 16, 64);
        v += __shfl_xor(v, 32, 64);
        if (lane < 16) {
            float z = v + bd0;
            out[rowBase + lane] = z > 0.f ? z : (__expf(z) - 1.0f);
        }
    }
}

extern "C" void kernel_launch(void* const* d_in, const int* in_sizes, int n_in,
                              void* d_out, int out_size, void* d_ws, size_t ws_size,
                              hipStream_t stream) {
    const float* x  = (const float*)d_in[0];
    const float* Wl = (const float*)d_in[1];
    const float* bl = (const float*)d_in[2];
    const float* Wd = (const float*)d_in[3];
    const float* bd = (const float*)d_in[4];
    float* out = (float*)d_out;

    const int rows = out_size;              // B = 16384
    const int grid = (rows + 15) / 16;      // 16 rows per 128-thread block
    hipLaunchKernelGGL(lstm_fused, dim3(grid), dim3(128), 0, stream,
                       x, Wl, bl, Wd, bd, out);
}

// Round 4
// 262.323 us; speedup vs baseline: 1.3368x; 1.3368x over previous
//
#include <hip/hip_runtime.h>
#include <stdint.h>

#define T_STEPS 256
#define F_IN 64
#define L2E 1.44269504f

typedef __bf16 bf16x8 __attribute__((ext_vector_type(8)));
typedef float f32x4 __attribute__((ext_vector_type(4)));
typedef uint32_t u32;
typedef uint32_t u32x2 __attribute__((ext_vector_type(2)));
typedef uint32_t u32x4 __attribute__((ext_vector_type(4)));

#define GLDS16(gp, lp)                                                         \
    __builtin_amdgcn_global_load_lds(                                          \
        (const __attribute__((address_space(1))) unsigned int*)(gp),           \
        (__attribute__((address_space(3))) unsigned int*)(lp), 16, 0, 0)

static __device__ __forceinline__ u32 pk2(float lo, float hi) {
    unsigned short a = __builtin_bit_cast(unsigned short, (__bf16)lo);
    unsigned short b = __builtin_bit_cast(unsigned short, (__bf16)hi);
    return (u32)a | ((u32)b << 16);
}

// 2 waves per 16-row tile, split by hidden UNIT (cells never cross waves):
//   wave 0: units 0..15  -> gate tiles q = 0,2,4,6 (i,j,f,o for units 0..15)
//   wave 1: units 16..31 -> gate tiles q = 1,3,5,7
// Transposed MFMA: gates^T[g][16] = W^T[g][96] @ [x|h]^T[96][16]
// A-frag (W^T): elem j of lane l -> W^T[gate=q*16+(l&15)][k=(l>>4)*8+j]
// B-frag (x/h): elem j of lane l -> [x|h]^T[k=(l>>4)*8+j][batch=l&15]
// D          : elem r of lane l -> gates^T[gate=q*16+(l>>4)*4+r][batch=l&15]
// h published per step into double-buffered hf[par] (one barrier per step).
__global__ __launch_bounds__(128, 2)
void lstm_fused(const float* __restrict__ x,
                const float* __restrict__ Wl,   // [96][128]
                const float* __restrict__ bl,   // [128]
                const float* __restrict__ Wd,   // [32]
                const float* __restrict__ bd,   // [1]
                float* __restrict__ out)        // [B]
{
    __shared__ __align__(16) float  xs[4][1024];   // 16 KB x ring, shared by both waves
    __shared__ __align__(16) __bf16 hf[2][64][8];  // h in MFMA B-frag layout, dbuf

    const int lane = threadIdx.x & 63;
    const int wid  = threadIdx.x >> 6;             // unit-half owner
    const int cl   = lane & 15;
    const int g4   = lane >> 4;
    const int rowBase = blockIdx.x * 16;

    // ---- this wave's 12 W^T A-fragments (q = 2*qi + wid) ----
    bf16x8 wfrag[3][4];
#pragma unroll
    for (int kc = 0; kc < 3; ++kc) {
#pragma unroll
        for (int qi = 0; qi < 4; ++qi) {
            bf16x8 v;
#pragma unroll
            for (int j = 0; j < 8; ++j)
                v[j] = (__bf16)Wl[(kc * 32 + g4 * 8 + j) * 128 + (2 * qi + wid) * 16 + cl];
            wfrag[kc][qi] = v;
        }
    }

    // ---- folded bias constants; this lane's units u = wid*16 + g4*4 + r ----
    float KI[4], KJ[4], KF[4], KO[4];
    {
        const int u0 = wid * 16 + g4 * 4;
#pragma unroll
        for (int r = 0; r < 4; ++r) {
            KI[r] = -L2E        *  bl[      u0 + r];
            KJ[r] = -2.0f * L2E *  bl[ 32 + u0 + r];
            KF[r] = -L2E        * (bl[ 64 + u0 + r] + 1.0f);
            KO[r] = -L2E        *  bl[ 96 + u0 + r];
        }
    }
    const float bd0 = bd[0];
    const f32x4 wdA = *(const f32x4*)(Wd + g4 * 8);
    const f32x4 wdB = *(const f32x4*)(Wd + g4 * 8 + 4);

    // per-lane pre-swizzled global base; this wave fetches float-chunks [wid*32, wid*32+32)
    const float* gbase = x + (size_t)(rowBase + (lane >> 2)) * (size_t)(T_STEPS * F_IN)
                           + (size_t)(((lane & 3) ^ ((lane >> 3) & 3)) * 4);

    // h0 = 0 (only hf[0] is read before first write)
    if (threadIdx.x < 64)
        *reinterpret_cast<u32x4*>(&hf[0][threadIdx.x][0]) = u32x4{0u, 0u, 0u, 0u};

    asm volatile("s_waitcnt vmcnt(0)" ::: "memory");   // drain setup loads for exact counting
    __builtin_amdgcn_sched_barrier(0);

    // prologue prefetch: slots 0..2, 2 loads/wave/slot
#pragma unroll
    for (int s = 0; s < 3; ++s) {
        const float* gp = gbase + s * F_IN + wid * 32;
        GLDS16(gp,      &xs[s][wid * 512]);
        GLDS16(gp + 16, &xs[s][wid * 512 + 256]);
    }

    asm volatile("s_waitcnt vmcnt(4) lgkmcnt(0)" ::: "memory");  // slot0 (own) + hf zeros done
    __builtin_amdgcn_sched_barrier(0);
    __builtin_amdgcn_s_barrier();
    __builtin_amdgcn_sched_barrier(0);

    const int swz = (cl >> 1) & 3;
    const int c0  = ((g4 & 1) * 2)     ^ swz;
    const int c1  = ((g4 & 1) * 2 + 1) ^ swz;
    const int kA  = (g4 >> 1) * 256 + cl * 16;
    const int kB  = kA + 512;
    const f32x4 z4 = {0.f, 0.f, 0.f, 0.f};

    // h-publish slot: unit u = wid*16 + g4*4 + r -> hf row (2*wid + (g4>>1))*16 + cl, elems (g4&1)*4 ..+3
    const int tT = (2 * wid + (g4 >> 1)) * 16 + cl;
    const int e0 = (g4 & 1) * 4;

    float c_st[4] = {0.f, 0.f, 0.f, 0.f};

#define STEP(TT, SLOT) do {                                                    \
    const int par = (SLOT) & 1;                                                \
    /* reads FIRST (any conservative vmcnt drain only hits >=1-step-old loads) */ \
    const float* sl = &xs[SLOT][0];                                            \
    f32x4 xr0 = *(const f32x4*)(sl + kA + c0 * 4);                             \
    f32x4 xr1 = *(const f32x4*)(sl + kA + c1 * 4);                             \
    f32x4 xr2 = *(const f32x4*)(sl + kB + c0 * 4);                             \
    f32x4 xr3 = *(const f32x4*)(sl + kB + c1 * 4);                             \
    bf16x8 ah = *reinterpret_cast<const bf16x8*>(&hf[par][lane][0]);           \
    /* issue prefetch for t+3 */                                               \
    const int tpf = ((TT) + 3 < T_STEPS) ? (TT) + 3 : T_STEPS - 1;             \
    const float* gp = gbase + tpf * F_IN + wid * 32;                           \
    GLDS16(gp,      &xs[((SLOT)+3)&3][wid * 512]);                             \
    GLDS16(gp + 16, &xs[((SLOT)+3)&3][wid * 512 + 256]);                       \
    bf16x8 ax0, ax1;                                                           \
    _Pragma("unroll")                                                          \
    for (int j = 0; j < 4; ++j) {                                              \
        ax0[j]     = (__bf16)xr0[j];                                           \
        ax0[4 + j] = (__bf16)xr1[j];                                           \
        ax1[j]     = (__bf16)xr2[j];                                           \
        ax1[4 + j] = (__bf16)xr3[j];                                           \
    }                                                                          \
    f32x4 acc[4];                                                              \
    __builtin_amdgcn_s_setprio(1);                                             \
    _Pragma("unroll")                                                          \
    for (int qi = 0; qi < 4; ++qi) {                                           \
        f32x4 a = __builtin_amdgcn_mfma_f32_16x16x32_bf16(wfrag[0][qi], ax0, z4, 0, 0, 0); \
        a = __builtin_amdgcn_mfma_f32_16x16x32_bf16(wfrag[1][qi], ax1, a, 0, 0, 0);        \
        a = __builtin_amdgcn_mfma_f32_16x16x32_bf16(wfrag[2][qi], ah,  a, 0, 0, 0);        \
        acc[qi] = a;                                                           \
    }                                                                          \
    __builtin_amdgcn_s_setprio(0);                                             \
    /* full cells in-wave: P = sig(i)tanh(j), S = sig(f'), h = tanh(c)sig(o) */\
    float hh[4];                                                               \
    _Pragma("unroll")                                                          \
    for (int r = 0; r < 4; ++r) {                                              \
        float I  = __builtin_amdgcn_exp2f(__builtin_fmaf(acc[0][r], -L2E,        KI[r])); \
        float J  = __builtin_amdgcn_exp2f(__builtin_fmaf(acc[1][r], -2.0f * L2E, KJ[r])); \
        float P  = (1.0f - J) * __builtin_amdgcn_rcpf((1.0f + I) * (1.0f + J)); \
        float Fv = __builtin_amdgcn_exp2f(__builtin_fmaf(acc[2][r], -L2E,        KF[r])); \
        float S  = __builtin_amdgcn_rcpf(1.0f + Fv);                           \
        float cn = __builtin_fmaf(c_st[r], S, P);                              \
        float C  = __builtin_amdgcn_exp2f(-2.0f * L2E * cn);                   \
        float O  = __builtin_amdgcn_exp2f(__builtin_fmaf(acc[3][r], -L2E,      KO[r])); \
        hh[r] = (1.0f - C) * __builtin_amdgcn_rcpf((1.0f + C) * (1.0f + O));   \
        c_st[r] = cn;                                                          \
    }                                                                          \
    *reinterpret_cast<u32x2*>(&hf[par ^ 1][tT][e0]) =                          \
        u32x2{pk2(hh[0], hh[1]), pk2(hh[2], hh[3])};                           \
    asm volatile("s_waitcnt vmcnt(4) lgkmcnt(0)" ::: "memory");                \
    __builtin_amdgcn_sched_barrier(0);                                         \
    __builtin_amdgcn_s_barrier();                                              \
    __builtin_amdgcn_sched_barrier(0);                                         \
} while (0)

    for (int t = 0; t < T_STEPS; t += 4) {
        STEP(t,     0);
        STEP(t + 1, 1);
        STEP(t + 2, 2);
        STEP(t + 3, 3);
    }
#undef STEP

    // ---- epilogue: out[b] = ELU(sum_u h[u]*Wd[u] + bd) ----
    // T_STEPS even -> final h is in hf[0]; published by the loop's last barrier.
    if (wid == 0) {
        bf16x8 hfin = *reinterpret_cast<const bf16x8*>(&hf[0][lane][0]);
        float v = 0.f;
#pragma unroll
        for (int j = 0; j < 4; ++j) {
            v = __builtin_fmaf((float)hfin[j],     wdA[j], v);
            v = __builtin_fmaf((float)hfin[4 + j], wdB[j], v);
        }
        v += __shfl_xor(v, 16, 64);
        v += __shfl_xor(v, 32, 64);
        if (lane < 16) {
            float z = v + bd0;
            out[rowBase + lane] = z > 0.f ? z : (__expf(z) - 1.0f);
        }
    }
}

extern "C" void kernel_launch(void* const* d_in, const int* in_sizes, int n_in,
                              void* d_out, int out_size, void* d_ws, size_t ws_size,
                              hipStream_t stream) {
    const float* x  = (const float*)d_in[0];
    const float* Wl = (const float*)d_in[1];
    const float* bl = (const float*)d_in[2];
    const float* Wd = (const float*)d_in[3];
    const float* bd = (const float*)d_in[4];
    float* out = (float*)d_out;

    const int rows = out_size;              // B = 16384
    const int grid = (rows + 15) / 16;      // 16 rows per 128-thread block (2 waves/tile)
    hipLaunchKernelGGL(lstm_fused, dim3(grid), dim3(128), 0, stream,
                       x, Wl, bl, Wd, bd, out);
}